// Round 12
// baseline (128.140 us; speedup 1.0000x reference)
//
#include <hip/hip_runtime.h>

#define Nn 2048
#define FIN 512
#define FO 64
#define SHIFT 20.0f
#define NIT 64                // i-tiles of 32
#define NJT 32                // j-tiles of 64 (partial-slice count, reduce unchanged)
#define HS 68                 // hi fp32 row stride (floats): 272B
#define HJS 68                // hj bf16 row stride (shorts): 136B
#define PTS3 36               // pT bf16 row stride (shorts): [64 j][32 i + pad]
#define ZTOT (Nn * FO + Nn)   // osum + lsum floats (fallback path only)

// hi fp32 swizzle (r4-proven family, f4-block XOR), write/read consistent
#define HX(r, f) ((r) * HS + ((((f) >> 2) ^ (((r) >> 2) & 15)) << 2))
// hj bf16 swizzle: 8-short (b64) blocks XOR'd with (r>>2); stride 68 spreads rows mod 128B
#define HJX(r, f) ((r) * HJS + ((((f) >> 3) ^ (((r) >> 2) & 7)) << 3) + ((f) & 7))
// pT bf16 [j][i]: i>>3 == wave id -> XOR with j&3 keeps each wave's cells physically
// wave-private (blocks {w^(j&3)} disjoint across w) => same-wave write->read, no barrier
#define PXI(j, i) ((j) * PTS3 + ((((i) >> 3) ^ ((j) & 3)) << 3) + ((i) & 7))

__device__ __forceinline__ unsigned pk2(float x, float y) {   // 2 f32 -> packed bf16 (RNE)
    unsigned r;
    asm("v_cvt_pk_bf16_f32 %0, %1, %2" : "=v"(r) : "v"(x), "v"(y));
    return r;
}
__device__ __forceinline__ float bflo(unsigned u) { return __uint_as_float(u << 16); }
__device__ __forceinline__ float bfhi(unsigned u) { return __uint_as_float(u & 0xffff0000u); }

// ---------------- K1: h = x @ W  (proven) + optional zeroing (fallback path) ----------------
__global__ __launch_bounds__(256) void gat_xw(const float* __restrict__ x,
                                              const float* __restrict__ W,
                                              float* __restrict__ h,
                                              float* __restrict__ z) {
    const int gt = blockIdx.x * 256 + threadIdx.x;
    if (z != nullptr && gt < ZTOT) z[gt] = 0.f;

    __shared__ float part[2][2][FO];
    const int wave = threadIdx.x >> 6;
    const int lane = threadIdx.x & 63;
    const int rs = wave >> 1;
    const int kh = wave & 1;
    int row = blockIdx.x * 2 + rs;
    row = __builtin_amdgcn_readfirstlane(row);
    const float* xr = x + (size_t)row * FIN + kh * (FIN / 2);
    const float* Wp = W + (size_t)kh * (FIN / 2) * FO;
    float acc = 0.f;
#pragma unroll 2
    for (int k = 0; k < FIN / 2; k += 8) {
        float4 xa = *(const float4*)(xr + k);
        float4 xb = *(const float4*)(xr + k + 4);
        acc = fmaf(xa.x, Wp[(k + 0) * FO + lane], acc);
        acc = fmaf(xa.y, Wp[(k + 1) * FO + lane], acc);
        acc = fmaf(xa.z, Wp[(k + 2) * FO + lane], acc);
        acc = fmaf(xa.w, Wp[(k + 3) * FO + lane], acc);
        acc = fmaf(xb.x, Wp[(k + 4) * FO + lane], acc);
        acc = fmaf(xb.y, Wp[(k + 5) * FO + lane], acc);
        acc = fmaf(xb.z, Wp[(k + 6) * FO + lane], acc);
        acc = fmaf(xb.w, Wp[(k + 7) * FO + lane], acc);
    }
    part[rs][kh][lane] = acc;
    __syncthreads();
    if (threadIdx.x < 128) {
        const int r2 = threadIdx.x >> 6;
        const int l2 = threadIdx.x & 63;
        h[((size_t)blockIdx.x * 2 + r2) * FO + l2] = part[r2][0][l2] + part[r2][1][l2];
    }
}

// ---------------- K2: thin-wave attn -- 32i x 64j tiles, 2048 blocks, 32 waves/CU ----------------
// The 4x4-per-lane structure caps the grid at 4096 waves = 16/CU (grid-limited; r2..r11
// occupancy levers were mirages). This kernel halves per-wave work (wave = 8i x 64j,
// lane = 2i x 4j) to create 8192 waves = 32/CU, trading ~1.4x DS instrs/cell for 2x
// latency-hiding. hi fp32 HX (proven), hj bf16 HJX (r10/r11 numerics), pT bf16 unioned
// over hi (B1 fence); pT stripes are wave-private via PXI's XOR -> same-wave write->read.
// po slices stay 32 (jt): it-halves write disjoint rows; gat_reduce unchanged.
template <bool ATOMIC>
__global__ __launch_bounds__(256, 8) void gat_attn12(const float* __restrict__ h,
                                                     const int* __restrict__ adj,
                                                     const float* __restrict__ a,
                                                     float* __restrict__ po,
                                                     float* __restrict__ pl) {
    __shared__ __align__(16) float hi_s[32 * HS];     // 8704B fp32; pT16 aliases after B1
    __shared__ __align__(16) short hj16[64 * HJS];    // 8704B bf16
    __shared__ float a_s[FO];
    short* pT16 = (short*)hi_s;                       // [64][PTS3] bf16, PXI swizzle

    const int tid = threadIdx.x;
    const int w = tid >> 6;
    const int lane = tid & 63;
    const int li = lane & 3;                 // i-pair group: i_loc = 8w + 2*li + d
    const int lj = lane >> 2;                // [0,16): j-quad base j = 4*lj
    const int it = blockIdx.x >> 5;          // 0..63
    const int jt = blockIdx.x & (NJT - 1);   // 0..31
    const int ib = it * 32;
    const int jb = jt * 64;
    const int iw = 8 * w;
    const int i0 = iw + 2 * li;              // lane's wave-local row base (2 rows)

    // stage hi (32 x 64 fp32, HX): 512 float4 / 256 thr = 2 each
    for (int g4 = tid; g4 < 512; g4 += 256) {
        const int row = g4 >> 4;
        const int f0 = (g4 & 15) * 4;
        *(float4*)&hi_s[HX(row, f0)] = *(const float4*)(h + (size_t)ib * FO + (size_t)g4 * 4);
    }
    // stage hj (64 x 64 bf16, HJX): 1024 float4 -> uint2 / 256 thr = 4 each
    for (int g4 = tid; g4 < 1024; g4 += 256) {
        const int row = g4 >> 4;
        const int f0 = (g4 & 15) * 4;
        const float4 u = *(const float4*)(h + (size_t)jb * FO + (size_t)g4 * 4);
        uint2 pk;
        pk.x = pk2(u.x, u.y);
        pk.y = pk2(u.z, u.w);
        *(uint2*)&hj16[HJX(row, f0)] = pk;
    }
    if (tid < FO) a_s[tid] = a[tid];
    __syncthreads();   // B0

    // ---- e-phase: e[di][dj] = sum_f a_f * |hi - hj| ; lane = 2i x 4j ----
    float e[2][4];
#pragma unroll
    for (int di = 0; di < 2; di++)
#pragma unroll
        for (int dj = 0; dj < 4; dj++) e[di][dj] = 0.f;

#pragma unroll 4
    for (int f4 = 0; f4 < 16; f4++) {
        const float4 av = *(const float4*)&a_s[f4 * 4];
        float4 hi4[2], hj4[4];
#pragma unroll
        for (int d = 0; d < 2; d++)
            hi4[d] = *(const float4*)&hi_s[HX(i0 + d, f4 * 4)];
#pragma unroll
        for (int d = 0; d < 4; d++) {
            const uint2 hw = *(const uint2*)&hj16[HJX(4 * lj + d, f4 * 4)];
            hj4[d].x = bflo(hw.x); hj4[d].y = bfhi(hw.x);
            hj4[d].z = bflo(hw.y); hj4[d].w = bfhi(hw.y);
        }
#pragma unroll
        for (int di = 0; di < 2; di++)
#pragma unroll
            for (int dj = 0; dj < 4; dj++) {
                e[di][dj] = fmaf(fabsf(hi4[di].x - hj4[dj].x), av.x, e[di][dj]);
                e[di][dj] = fmaf(fabsf(hi4[di].y - hj4[dj].y), av.y, e[di][dj]);
                e[di][dj] = fmaf(fabsf(hi4[di].z - hj4[dj].z), av.z, e[di][dj]);
                e[di][dj] = fmaf(fabsf(hi4[di].w - hj4[dj].w), av.w, e[di][dj]);
            }
    }

    // ---- p = adj ? exp(relu(e) - SHIFT) : 0 ; fp32 row sums ----
    float ls2[2] = {0.f, 0.f};
#pragma unroll
    for (int di = 0; di < 2; di++) {
        const int4 am = *(const int4*)(adj + (size_t)(ib + i0 + di) * Nn + (jb + 4 * lj));
        const int* ap = (const int*)&am;
#pragma unroll
        for (int dj = 0; dj < 4; dj++) {
            const float p = (ap[dj] > 0) ? __expf(fmaxf(e[di][dj], 0.f) - SHIFT) : 0.f;
            e[di][dj] = p;
            ls2[di] += p;
        }
    }

    __syncthreads();   // B1: all waves done reading hi_s -> pT16 may overwrite (union)

    // pT writes: b32 per (j, i-pair); wave-private physical blocks via PXI
#pragma unroll
    for (int dj = 0; dj < 4; dj++) {
        const unsigned pk = pk2(e[0][dj], e[1][dj]);
        *(unsigned*)&pT16[PXI(4 * lj + dj, i0)] = pk;
    }

    // ---- PV: lane -> (2i x 4f): i = ib+i0+d, f = 4*lj+c ; pT b32 + hj b64, same-wave pT ----
    float pv[2][4];
#pragma unroll
    for (int di = 0; di < 2; di++)
#pragma unroll
        for (int c = 0; c < 4; c++) pv[di][c] = 0.f;

#pragma unroll 4
    for (int j = 0; j < 64; j++) {
        const unsigned pw = *(const unsigned*)&pT16[PXI(j, i0)];
        const float p0 = bflo(pw), p1 = bfhi(pw);
        const uint2 hw = *(const uint2*)&hj16[HJX(j, 4 * lj)];
        const float h0 = bflo(hw.x), h1 = bfhi(hw.x), h2 = bflo(hw.y), h3 = bfhi(hw.y);
        pv[0][0] = fmaf(p0, h0, pv[0][0]); pv[0][1] = fmaf(p0, h1, pv[0][1]);
        pv[0][2] = fmaf(p0, h2, pv[0][2]); pv[0][3] = fmaf(p0, h3, pv[0][3]);
        pv[1][0] = fmaf(p1, h0, pv[1][0]); pv[1][1] = fmaf(p1, h1, pv[1][1]);
        pv[1][2] = fmaf(p1, h2, pv[1][2]); pv[1][3] = fmaf(p1, h3, pv[1][3]);
    }

    // ---- epilogue: reduce ls over lj (16 lanes: xor 4,8,16,32); partial stores ----
#pragma unroll
    for (int di = 0; di < 2; di++) {
        float v = ls2[di];
        v += __shfl_xor(v, 4, 64);
        v += __shfl_xor(v, 8, 64);
        v += __shfl_xor(v, 16, 64);
        v += __shfl_xor(v, 32, 64);
        ls2[di] = v;
    }

    if constexpr (!ATOMIC) {
        if (lj == 0) {
#pragma unroll
            for (int di = 0; di < 2; di++)
                pl[(size_t)jt * Nn + (ib + i0 + di)] = ls2[di];
        }
#pragma unroll
        for (int di = 0; di < 2; di++)
            *(float4*)&po[((size_t)jt * Nn + (ib + i0 + di)) * FO + 4 * lj] =
                make_float4(pv[di][0], pv[di][1], pv[di][2], pv[di][3]);
    } else {
        if (lj == 0) {
#pragma unroll
            for (int di = 0; di < 2; di++)
                atomicAdd(&pl[ib + i0 + di], ls2[di]);
        }
#pragma unroll
        for (int di = 0; di < 2; di++) {
#pragma unroll
            for (int c = 0; c < 4; c++)
                atomicAdd(&po[(size_t)(ib + i0 + di) * FO + 4 * lj + c], pv[di][c]);
        }
    }
}

// ---------------- K3: out = relu(sum_jt po / sum_jt pl) ----------------
__global__ __launch_bounds__(256) void gat_reduce(const float* __restrict__ po,
                                                  const float* __restrict__ pl,
                                                  float* __restrict__ out) {
    const int t = blockIdx.x * 256 + threadIdx.x;   // grid 512 -> 131072 = Nn*FO
    const int i = t >> 6;
    float s = 0.f;
#pragma unroll
    for (int p = 0; p < NJT; p++) s += po[(size_t)p * (Nn * FO) + t];
    float l = 0.f;
#pragma unroll
    for (int p = 0; p < NJT; p++) l += pl[p * Nn + i];   // wave-uniform addr -> broadcast
    out[t] = fmaxf(s / l, 0.f);
}

// ---------------- fallback K3: out = relu(osum / lsum) ----------------
__global__ __launch_bounds__(256) void gat_fin(const float* __restrict__ osum,
                                               const float* __restrict__ lsum,
                                               float* __restrict__ out) {
    const int t = blockIdx.x * 256 + threadIdx.x;
    out[t] = fmaxf(osum[t] / lsum[t >> 6], 0.f);
}

extern "C" void kernel_launch(void* const* d_in, const int* in_sizes, int n_in,
                              void* d_out, int out_size, void* d_ws, size_t ws_size,
                              hipStream_t stream) {
    const float* x   = (const float*)d_in[0];
    const int*   adj = (const int*)d_in[1];
    const float* W   = (const float*)d_in[2];
    const float* a   = (const float*)d_in[3];
    float* out = (float*)d_out;

    float* h = (float*)d_ws;                                   // Nn*FO floats
    const size_t need = ((size_t)Nn * FO + (size_t)NJT * Nn * FO + (size_t)NJT * Nn) * 4;

    if (ws_size >= need) {
        // no-atomic path: private partials + reduction
        float* po = h + (size_t)Nn * FO;                       // NJT*Nn*FO floats
        float* pl = po + (size_t)NJT * Nn * FO;                // NJT*Nn floats
        gat_xw<<<dim3(1024), dim3(256), 0, stream>>>(x, W, h, nullptr);
        gat_attn12<false><<<dim3(NIT * NJT), dim3(256), 0, stream>>>(h, adj, a, po, pl);
        gat_reduce<<<dim3(512), dim3(256), 0, stream>>>(po, pl, out);
    } else {
        // fallback: atomic accumulation (1.06 MB workspace)
        float* osum = h + (size_t)Nn * FO;
        float* lsum = osum + (size_t)Nn * FO;
        gat_xw<<<dim3(1024), dim3(256), 0, stream>>>(x, W, h, osum);   // zeros osum+lsum
        gat_attn12<true><<<dim3(NIT * NJT), dim3(256), 0, stream>>>(h, adj, a, osum, lsum);
        gat_fin<<<dim3(512), dim3(256), 0, stream>>>(osum, lsum, out);
    }
}